// Round 2
// baseline (6277.099 us; speedup 1.0000x reference)
//
#include <hip/hip_runtime.h>

#define B_    1024
#define H_    2112
#define FH    8448   // 4*H
#define IN_   99
#define TENC  50
#define SEQ   25
#define K0    2240   // 128 (padded IN) + 2112
#define K1    4224   // 2112 + 2112
#define LDX0  2240
#define LDX1  4224

typedef __bf16 bf16;
typedef __bf16 bf16x8 __attribute__((ext_vector_type(8)));
typedef __bf16 bf16x4 __attribute__((ext_vector_type(4)));
typedef float  f32x4  __attribute__((ext_vector_type(4)));

__device__ __forceinline__ void gload_lds16(const void* g, void* l) {
  __builtin_amdgcn_global_load_lds(
      (const __attribute__((address_space(1))) void*)g,
      (__attribute__((address_space(3))) void*)l, 16, 0, 0);
}

__device__ __forceinline__ float sigf(float x) { return 1.f / (1.f + __expf(-x)); }
__device__ __forceinline__ float tanhfast(float x) { return 1.f - 2.f / (__expf(2.f * x) + 1.f); }

// ---------------------------------------------------------------------------
// Fused gates-GEMM + LSTM cell.  128(M) x 32(h) tile => 128 gate-cols (i,f,g,o).
// Depth-2 counted-vmcnt pipeline + T2 swizzle (pre-swizzled global source,
// linear LDS dest, swizzled ds_read).  Grid: 1D 528 blocks, XCD-chunked swizzle.
// ---------------------------------------------------------------------------
__global__ __launch_bounds__(256, 2)
void lstm_gemm_cell(const bf16* __restrict__ X, int lda, int K,
                    const bf16* __restrict__ W,
                    const float* __restrict__ bsum,   // 4H combined bias
                    float* __restrict__ Cst,          // B x H fp32, in-place
                    bf16* __restrict__ d1, int ld1,   // h_new dest 1
                    bf16* __restrict__ d2, int ld2)   // h_new dest 2 (optional)
{
  __shared__ __align__(16) bf16 As[2][128 * 64];
  __shared__ __align__(16) bf16 Bs[2][128 * 64];

  // XCD-chunked swizzle: 528 blocks, 8 XCDs, chunk = 66.  Same-panel (same hc0)
  // M-blocks get consecutive vids -> same XCD -> weight panel L2-resident.
  const int cpx = gridDim.x >> 3;                       // 66
  const int vid = (blockIdx.x & 7) * cpx + (blockIdx.x >> 3);
  const int hc0 = (vid >> 3) * 32;
  const int m0  = (vid & 7) * 128;

  const int tid  = threadIdx.x;
  const int arow = tid >> 3;                            // 0..31
  // T2: pre-swizzled source column. LDS physical unit q holds logical unit
  // q ^ (row&7); reader XORs the same.
  const int sq8  = (((tid & 7) ^ (arow & 7))) * 8;      // bf16 elems

  const bf16* Ab = X + (size_t)(m0 + arow) * lda + sq8;
  const bf16* Bb = W + (size_t)(hc0 + arow) * K + sq8;

  const int lane = tid & 63;
  const int wv = tid >> 6;
  const int wm = wv >> 1, wn = wv & 1;
  const int lr = lane & 15, lq = lane >> 4;
  const int xs = lane & 7;                              // == lr & 7
  // swizzled fragment column offsets (bf16 elems) for kc = 0,1
  const int cof0 = ((lq ^ xs)) * 8;
  const int cof1 = (((4 + lq) ^ xs)) * 8;

  f32x4 acc[4][4];
#pragma unroll
  for (int a = 0; a < 4; ++a)
#pragma unroll
    for (int b = 0; b < 4; ++b) acc[a][b] = (f32x4){0.f, 0.f, 0.f, 0.f};

  auto stage = [&](int kt, int buf) {
    const int ko = kt * 64;
    bf16* ad = &As[buf][tid * 8];
    bf16* bd = &Bs[buf][tid * 8];
#pragma unroll
    for (int it = 0; it < 4; ++it) {
      gload_lds16(Ab + (size_t)it * 32 * lda + ko, ad + it * 2048);
      gload_lds16(Bb + (size_t)it * H_ * K + ko,   bd + it * 2048);
    }
  };

  auto compute = [&](int buf) {
    const bf16* Ap = &As[buf][0];
    const bf16* Bp = &Bs[buf][0];
    bf16x8 af[4][2], bfr[4][2];
#pragma unroll
    for (int mi = 0; mi < 4; ++mi) {
      const int r = (wm * 64 + mi * 16 + lr) * 64;
      af[mi][0] = *(const bf16x8*)&Ap[r + cof0];
      af[mi][1] = *(const bf16x8*)&Ap[r + cof1];
    }
#pragma unroll
    for (int ni = 0; ni < 4; ++ni) {
      const int r = (ni * 32 + wn * 16 + lr) * 64;
      bfr[ni][0] = *(const bf16x8*)&Bp[r + cof0];
      bfr[ni][1] = *(const bf16x8*)&Bp[r + cof1];
    }
    __builtin_amdgcn_s_setprio(1);
#pragma unroll
    for (int mi = 0; mi < 4; ++mi)
#pragma unroll
      for (int ni = 0; ni < 4; ++ni)
#pragma unroll
        for (int kc = 0; kc < 2; ++kc)
          acc[mi][ni] = __builtin_amdgcn_mfma_f32_16x16x32_bf16(
              af[mi][kc], bfr[ni][kc], acc[mi][ni], 0, 0, 0);
    __builtin_amdgcn_s_setprio(0);
  };

  const int KT = K >> 6;   // >= 35
  stage(0, 0);
  stage(1, 1);
  for (int kt = 0; kt < KT - 2; ++kt) {
    asm volatile("s_waitcnt vmcnt(8)" ::: "memory");
    __builtin_amdgcn_s_barrier();
    asm volatile("" ::: "memory");
    compute(kt & 1);
    asm volatile("" ::: "memory");
    __builtin_amdgcn_s_barrier();
    asm volatile("" ::: "memory");
    stage(kt + 2, kt & 1);
  }
  asm volatile("s_waitcnt vmcnt(8)" ::: "memory");
  __builtin_amdgcn_s_barrier();
  asm volatile("" ::: "memory");
  compute(KT & 1);                       // tile KT-2
  asm volatile("s_waitcnt vmcnt(0)" ::: "memory");
  __builtin_amdgcn_s_barrier();
  asm volatile("" ::: "memory");
  compute((KT - 1) & 1);                 // tile KT-1

  // epilogue: LSTM cell
  const int hc = hc0 + wn * 16 + lr;
  const float bi = bsum[hc];
  const float bff = bsum[H_ + hc];
  const float bg = bsum[2 * H_ + hc];
  const float bo = bsum[3 * H_ + hc];

#pragma unroll
  for (int mi = 0; mi < 4; ++mi) {
#pragma unroll
    for (int r = 0; r < 4; ++r) {
      const int m = m0 + wm * 64 + mi * 16 + lq * 4 + r;
      const float gi = acc[mi][0][r] + bi;
      const float gf = acc[mi][1][r] + bff;
      const float gg = acc[mi][2][r] + bg;
      const float go = acc[mi][3][r] + bo;
      const size_t ci = (size_t)m * H_ + hc;
      const float c_old = Cst[ci];
      const float cn = sigf(gf) * c_old + sigf(gi) * tanhfast(gg);
      const float hn = sigf(go) * tanhfast(cn);
      Cst[ci] = cn;
      const bf16 hb = (bf16)hn;
      d1[(size_t)m * ld1 + hc] = hb;
      if (d2) d2[(size_t)m * ld2 + hc] = hb;
    }
  }
}

// ---------------------------------------------------------------------------
// out-GEMM: pre = h1n @ W_out + b_out + prev ; writes d_out, prev, X0next bf16.
// 64 blocks of 16 rows; K=2112 split {9,8,8,8}x64 across the 4 waves; LDS reduce.
// ---------------------------------------------------------------------------
__global__ __launch_bounds__(256, 1)
void out_gemm(const bf16* __restrict__ Hin,   // X1next + 2112, row stride 4224
              const bf16* __restrict__ Wo,    // 112 x 2112 (transposed W_out, zero-padded)
              const float* __restrict__ b_out,
              float* __restrict__ prev,       // B x 112 fp32
              bf16* __restrict__ X0n,         // write bf16 pre at cols 0..99
              float* __restrict__ out, int t)
{
  __shared__ float red[4][16][112];
  const int tid = threadIdx.x;
  const int m0 = blockIdx.x * 16;
  const int lane = tid & 63, wv = tid >> 6;
  const int lr = lane & 15, lq = lane >> 4, lk = lq * 8;

  f32x4 acc[7];
#pragma unroll
  for (int b = 0; b < 7; ++b) acc[b] = (f32x4){0.f, 0.f, 0.f, 0.f};

  const int start = (wv == 0) ? 0 : (1 + wv * 8);   // {0,9,17,25}
  const int cnt = (wv == 0) ? 9 : 8;                // 33 K-tiles of 64 total

  for (int kt = start; kt < start + cnt; ++kt) {
    const int ko = kt * 64;
    bf16x8 av[2], bv[7][2];
#pragma unroll
    for (int kc = 0; kc < 2; ++kc)
      av[kc] = *(const bf16x8*)&Hin[(size_t)(m0 + lr) * LDX1 + ko + kc * 32 + lk];
#pragma unroll
    for (int nf = 0; nf < 7; ++nf)
#pragma unroll
      for (int kc = 0; kc < 2; ++kc)
        bv[nf][kc] = *(const bf16x8*)&Wo[(size_t)(nf * 16 + lr) * H_ + ko + kc * 32 + lk];
#pragma unroll
    for (int nf = 0; nf < 7; ++nf)
#pragma unroll
      for (int kc = 0; kc < 2; ++kc)
        acc[nf] = __builtin_amdgcn_mfma_f32_16x16x32_bf16(av[kc], bv[nf][kc], acc[nf], 0, 0, 0);
  }

#pragma unroll
  for (int nf = 0; nf < 7; ++nf)
#pragma unroll
    for (int r = 0; r < 4; ++r)
      red[wv][lq * 4 + r][nf * 16 + lr] = acc[nf][r];
  __syncthreads();

  for (int idx = tid; idx < 16 * 112; idx += 256) {
    const int ml = idx / 112, n = idx - ml * 112;
    if (n < IN_) {
      const int m = m0 + ml;
      float s = red[0][ml][n] + red[1][ml][n] + red[2][ml][n] + red[3][ml][n] + b_out[n];
      const float pre = s + prev[m * 112 + n];
      prev[m * 112 + n] = pre;
      out[((size_t)m * SEQ + t) * IN_ + n] = pre;
      X0n[(size_t)m * LDX0 + n] = (bf16)pre;
    }
  }
}

// ---------------------------------------------------------------------------
// init: h0 = mean(hidden), h1 = (global_t + sum hidden)/51, c0 = c1 = mean(cell)
// ---------------------------------------------------------------------------
__global__ void init_state(const float* __restrict__ hs, const float* __restrict__ cs,
                           const float* __restrict__ gts,
                           bf16* __restrict__ X0a, bf16* __restrict__ X1a,
                           float* __restrict__ c0, float* __restrict__ c1)
{
  const int h4 = blockIdx.x * 256 + threadIdx.x;
  if (h4 >= 528) return;
  const int b = blockIdx.y;
  const float4* hp = (const float4*)(hs + (size_t)b * TENC * H_) + h4;
  const float4* cp = (const float4*)(cs + (size_t)b * TENC * H_) + h4;
  float4 sh = {0.f, 0.f, 0.f, 0.f}, sc = {0.f, 0.f, 0.f, 0.f};
  for (int tt = 0; tt < TENC; ++tt) {
    float4 a = hp[tt * 528];
    sh.x += a.x; sh.y += a.y; sh.z += a.z; sh.w += a.w;
    float4 c = cp[tt * 528];
    sc.x += c.x; sc.y += c.y; sc.z += c.z; sc.w += c.w;
  }
  const float4 g = ((const float4*)(gts + (size_t)b * H_))[h4];
  const float4 c0v = {sc.x / 50.f, sc.y / 50.f, sc.z / 50.f, sc.w / 50.f};
  ((float4*)(c0 + (size_t)b * H_))[h4] = c0v;
  ((float4*)(c1 + (size_t)b * H_))[h4] = c0v;
  bf16x4 h0b = {(bf16)(sh.x / 50.f), (bf16)(sh.y / 50.f), (bf16)(sh.z / 50.f), (bf16)(sh.w / 50.f)};
  *(bf16x4*)&X0a[(size_t)b * LDX0 + 128 + h4 * 4] = h0b;
  bf16x4 h1b = {(bf16)((sh.x + g.x) / 51.f), (bf16)((sh.y + g.y) / 51.f),
                (bf16)((sh.z + g.z) / 51.f), (bf16)((sh.w + g.w) / 51.f)};
  *(bf16x4*)&X1a[(size_t)b * LDX1 + 2112 + h4 * 4] = h1b;
}

__global__ void init_prev(const float* __restrict__ p, float* __restrict__ prev,
                          bf16* __restrict__ X0a, bf16* __restrict__ X0b)
{
  const int idx = blockIdx.x * 256 + threadIdx.x;   // B*128
  const int b = idx >> 7, n = idx & 127;
  const float v = (n < IN_) ? p[(size_t)b * IN_ + n] : 0.f;
  if (n < 112) prev[b * 112 + n] = v;
  X0a[(size_t)b * LDX0 + n] = (bf16)v;
  X0b[(size_t)b * LDX0 + n] = (bf16)0.f;   // pads (cols 99..128) stay zero; 0..99 overwritten step 0
}

// ---------------------------------------------------------------------------
// weight packing (fp32 -> bf16, concatenated / transposed)
// ---------------------------------------------------------------------------
__global__ void pack_w0(const float* __restrict__ Wih, const float* __restrict__ Whh,
                        bf16* __restrict__ Wc)
{
  const int n = blockIdx.x;
  const float* a = Wih + (size_t)n * IN_;
  const float* b = Whh + (size_t)n * H_;
  bf16* d = Wc + (size_t)n * K0;
  for (int k = threadIdx.x; k < K0; k += 256) {
    float v = (k < IN_) ? a[k] : ((k >= 128) ? b[k - 128] : 0.f);
    d[k] = (bf16)v;
  }
}

__global__ void pack_w1(const float* __restrict__ Wih, const float* __restrict__ Whh,
                        bf16* __restrict__ Wc)
{
  const int n = blockIdx.x;
  bf16* d = Wc + (size_t)n * K1;
  for (int k = threadIdx.x; k < K1; k += 256)
    d[k] = (bf16)((k < H_) ? Wih[(size_t)n * H_ + k] : Whh[(size_t)n * H_ + k - H_]);
}

__global__ void pack_wo(const float* __restrict__ W, bf16* __restrict__ Wo)
{
  const int n = blockIdx.x;   // 0..111
  for (int k = threadIdx.x; k < H_; k += 256)
    Wo[(size_t)n * H_ + k] = (n < IN_) ? (bf16)W[(size_t)k * IN_ + n] : (bf16)0.f;
}

__global__ void pack_bias(const float* __restrict__ bi0, const float* __restrict__ bh0,
                          const float* __restrict__ bi1, const float* __restrict__ bh1,
                          float* __restrict__ bs0, float* __restrict__ bs1)
{
  const int i = blockIdx.x * 256 + threadIdx.x;
  if (i < FH) { bs0[i] = bi0[i] + bh0[i]; bs1[i] = bi1[i] + bh1[i]; }
}

// ---------------------------------------------------------------------------
extern "C" void kernel_launch(void* const* d_in, const int* in_sizes, int n_in,
                              void* d_out, int out_size, void* d_ws, size_t ws_size,
                              hipStream_t stream)
{
  (void)in_sizes; (void)n_in; (void)out_size; (void)ws_size;
  const float* hs   = (const float*)d_in[0];
  const float* cs   = (const float*)d_in[1];
  const float* gts  = (const float*)d_in[2];
  const float* p    = (const float*)d_in[3];
  const float* Wih0 = (const float*)d_in[4];
  const float* bih0 = (const float*)d_in[5];
  const float* Whh0 = (const float*)d_in[6];
  const float* bhh0 = (const float*)d_in[7];
  const float* Wih1 = (const float*)d_in[8];
  const float* bih1 = (const float*)d_in[9];
  const float* Whh1 = (const float*)d_in[10];
  const float* bhh1 = (const float*)d_in[11];
  const float* Wout = (const float*)d_in[12];
  const float* bout = (const float*)d_in[13];
  float* out = (float*)d_out;

  char* ws = (char*)d_ws;
  size_t off = 0;
  auto alloc = [&](size_t bytes) -> void* {
    void* q = ws + off; off += (bytes + 255) & ~(size_t)255; return q;
  };
  bf16* Wc0 = (bf16*)alloc((size_t)FH * K0 * 2);
  bf16* Wc1 = (bf16*)alloc((size_t)FH * K1 * 2);
  bf16* Wo  = (bf16*)alloc((size_t)112 * H_ * 2);
  float* bs0 = (float*)alloc((size_t)FH * 4);
  float* bs1 = (float*)alloc((size_t)FH * 4);
  bf16* X0[2] = {(bf16*)alloc((size_t)B_ * LDX0 * 2), (bf16*)alloc((size_t)B_ * LDX0 * 2)};
  bf16* X1[2] = {(bf16*)alloc((size_t)B_ * LDX1 * 2), (bf16*)alloc((size_t)B_ * LDX1 * 2)};
  float* c0  = (float*)alloc((size_t)B_ * H_ * 4);
  float* c1  = (float*)alloc((size_t)B_ * H_ * 4);
  float* prev = (float*)alloc((size_t)B_ * 112 * 4);

  pack_w0<<<FH, 256, 0, stream>>>(Wih0, Whh0, Wc0);
  pack_w1<<<FH, 256, 0, stream>>>(Wih1, Whh1, Wc1);
  pack_wo<<<112, 256, 0, stream>>>(Wout, Wo);
  pack_bias<<<(FH + 255) / 256, 256, 0, stream>>>(bih0, bhh0, bih1, bhh1, bs0, bs1);
  init_prev<<<(B_ * 128) / 256, 256, 0, stream>>>(p, prev, X0[0], X0[1]);
  init_state<<<dim3(3, B_), 256, 0, stream>>>(hs, cs, gts, X0[0], X1[0], c0, c1);

  for (int t = 0; t < SEQ; ++t) {
    const int cur = t & 1, nxt = cur ^ 1;
    // layer 0: reads X0[cur] = [prev_bf | h0]; writes c0, h0n -> X1[cur] cols 0.. and X0[nxt] cols 128..
    lstm_gemm_cell<<<528, 256, 0, stream>>>(
        X0[cur], LDX0, K0, Wc0, bs0, c0, X1[cur], LDX1, X0[nxt] + 128, LDX0);
    // layer 1: reads X1[cur] = [h0n | h1]; writes c1, h1n -> X1[nxt] cols 2112..
    lstm_gemm_cell<<<528, 256, 0, stream>>>(
        X1[cur], LDX1, K1, Wc1, bs1, c1, X1[nxt] + 2112, LDX1, (bf16*)nullptr, 0);
    // out: pre = h1n @ W_out + b_out + prev; writes out[:,t,:], prev, X0[nxt] cols 0..99
    out_gemm<<<64, 256, 0, stream>>>(X1[nxt] + 2112, Wo, bout, prev, X0[nxt], out, t);
  }
}

// Round 3
// 5041.469 us; speedup vs baseline: 1.2451x; 1.2451x over previous
//
#include <hip/hip_runtime.h>

#define B_    1024
#define H_    2112
#define FH    8448   // 4*H
#define IN_   99
#define TENC  50
#define SEQ   25
#define K0    2240   // 128 (padded IN) + 2112
#define K1    4224   // 2112 + 2112
#define LDX0  2240
#define LDX1  4224

typedef __bf16 bf16;
typedef __bf16 bf16x8 __attribute__((ext_vector_type(8)));
typedef __bf16 bf16x4 __attribute__((ext_vector_type(4)));
typedef float  f32x4  __attribute__((ext_vector_type(4)));

__device__ __forceinline__ void gload_lds16(const void* g, void* l) {
  __builtin_amdgcn_global_load_lds(
      (const __attribute__((address_space(1))) void*)g,
      (__attribute__((address_space(3))) void*)l, 16, 0, 0);
}

__device__ __forceinline__ float sigf(float x) { return 1.f / (1.f + __expf(-x)); }
__device__ __forceinline__ float tanhfast(float x) { return 1.f - 2.f / (__expf(2.f * x) + 1.f); }

// ---------------------------------------------------------------------------
// Fused gates-GEMM + LSTM cell.
// Tile: 128(M) x 16(h) => 64 gate-cols (sections i,f,g,o at nf=0..3).
// 2 waves (128 thr), 24KB LDS -> ~6 blocks/CU resident; 1056 blocks (8M x 132h).
// Wave w covers rows w*64..+64: acc[mi 0..3][sec 0..3], 16 ds_read : 32 MFMA.
// Simple m97-style 2-barrier K-loop (compiler-scheduled).
// ---------------------------------------------------------------------------
__global__ __launch_bounds__(128, 3)
void lstm_gemm_cell(const bf16* __restrict__ X, int lda, int K,
                    const bf16* __restrict__ W,
                    const float* __restrict__ bsum,   // 4H combined bias
                    float* __restrict__ Cst,          // B x H fp32, in-place
                    bf16* __restrict__ d1, int ld1,   // h_new dest 1
                    bf16* __restrict__ d2, int ld2)   // h_new dest 2 (optional)
{
  __shared__ __align__(16) bf16 As[128 * 64];   // 16 KB
  __shared__ __align__(16) bf16 Bs[64 * 64];    //  8 KB

  // XCD-chunked: 1056 blocks, 132 consecutive vids per XCD; vid is hc-major so
  // the 8 same-weight-panel M-blocks are adjacent -> weight panel L2-resident.
  const int cpx = gridDim.x >> 3;                       // 132
  const int vid = (blockIdx.x & 7) * cpx + (blockIdx.x >> 3);
  const int hc0 = (vid >> 3) * 16;                      // 0..2096
  const int m0  = (vid & 7) * 128;

  const int tid  = threadIdx.x;                         // 0..127
  const int srow = tid >> 3;                            // 0..15
  const int scol = (tid & 7) * 8;                       // bf16 elems

  const bf16* Ab = X + (size_t)(m0 + srow) * lda + scol;
  const bf16* Bb = W + (size_t)(hc0 + srow) * K + scol; // + sec*H*K per section

  const int lane = tid & 63;
  const int w    = tid >> 6;                            // wave 0/1
  const int lr   = lane & 15, lq = lane >> 4;
  const int lk   = lq * 8;

  f32x4 acc[4][4];
#pragma unroll
  for (int a = 0; a < 4; ++a)
#pragma unroll
    for (int b = 0; b < 4; ++b) acc[a][b] = (f32x4){0.f, 0.f, 0.f, 0.f};

  const int KT = K >> 6;
  for (int kt = 0; kt < KT; ++kt) {
    const int ko = kt * 64;
    // A: 128 rows x 64 cols, 8 iters x (128 thr x 16B)
#pragma unroll
    for (int it = 0; it < 8; ++it)
      gload_lds16(Ab + (size_t)it * 16 * lda + ko, &As[it * 1024 + tid * 8]);
    // B: 64 gate-rows (4 sections x 16 h-rows) x 64 cols
#pragma unroll
    for (int it = 0; it < 4; ++it)
      gload_lds16(Bb + (size_t)it * H_ * K + ko, &Bs[it * 1024 + tid * 8]);
    __syncthreads();

    bf16x8 af[4][2], bfr[4][2];
#pragma unroll
    for (int mi = 0; mi < 4; ++mi) {
      const int r = (w * 64 + mi * 16 + lr) * 64;
      af[mi][0] = *(const bf16x8*)&As[r + lk];
      af[mi][1] = *(const bf16x8*)&As[r + 32 + lk];
    }
#pragma unroll
    for (int nf = 0; nf < 4; ++nf) {
      const int r = (nf * 16 + lr) * 64;
      bfr[nf][0] = *(const bf16x8*)&Bs[r + lk];
      bfr[nf][1] = *(const bf16x8*)&Bs[r + 32 + lk];
    }
#pragma unroll
    for (int mi = 0; mi < 4; ++mi)
#pragma unroll
      for (int nf = 0; nf < 4; ++nf)
#pragma unroll
        for (int kc = 0; kc < 2; ++kc)
          acc[mi][nf] = __builtin_amdgcn_mfma_f32_16x16x32_bf16(
              af[mi][kc], bfr[nf][kc], acc[mi][nf], 0, 0, 0);
    __syncthreads();
  }

  // epilogue: LSTM cell (lane owns h-col hc for 16 m-rows)
  const int hc = hc0 + lr;
  const float bi  = bsum[hc];
  const float bff = bsum[H_ + hc];
  const float bg  = bsum[2 * H_ + hc];
  const float bo  = bsum[3 * H_ + hc];

#pragma unroll
  for (int mi = 0; mi < 4; ++mi) {
#pragma unroll
    for (int r = 0; r < 4; ++r) {
      const int m = m0 + w * 64 + mi * 16 + lq * 4 + r;
      const float gi = acc[mi][0][r] + bi;
      const float gf = acc[mi][1][r] + bff;
      const float gg = acc[mi][2][r] + bg;
      const float go = acc[mi][3][r] + bo;
      const size_t ci = (size_t)m * H_ + hc;
      const float c_old = Cst[ci];
      const float cn = sigf(gf) * c_old + sigf(gi) * tanhfast(gg);
      const float hn = sigf(go) * tanhfast(cn);
      Cst[ci] = cn;
      const bf16 hb = (bf16)hn;
      d1[(size_t)m * ld1 + hc] = hb;
      if (d2) d2[(size_t)m * ld2 + hc] = hb;
    }
  }
}

// ---------------------------------------------------------------------------
// out-GEMM: pre = h1n @ W_out + b_out + prev ; writes d_out, prev, X0next bf16.
// 128 blocks of 8 rows (A-frag rows duplicated lr&7); K=2112 as 33 tiles of 64
// split {9,8,8,8} across 4 waves; LDS reduce.
// ---------------------------------------------------------------------------
__global__ __launch_bounds__(256, 1)
void out_gemm(const bf16* __restrict__ Hin,   // X1next + 2112, row stride 4224
              const bf16* __restrict__ Wo,    // 112 x 2112 (transposed W_out, zero-padded)
              const float* __restrict__ b_out,
              float* __restrict__ prev,       // B x 112 fp32
              bf16* __restrict__ X0n,         // write bf16 pre at cols 0..99
              float* __restrict__ out, int t)
{
  __shared__ float red[4][8][112];
  const int tid = threadIdx.x;
  const int m0 = blockIdx.x * 8;
  const int lane = tid & 63, wv = tid >> 6;
  const int lr = lane & 15, lq = lane >> 4, lk = lq * 8;

  f32x4 acc[7];
#pragma unroll
  for (int b = 0; b < 7; ++b) acc[b] = (f32x4){0.f, 0.f, 0.f, 0.f};

  const int start = (wv == 0) ? 0 : (1 + wv * 8);   // {0,9,17,25}
  const int cnt = (wv == 0) ? 9 : 8;                // 33 K-tiles of 64 total

  for (int kt = start; kt < start + cnt; ++kt) {
    const int ko = kt * 64;
    bf16x8 av[2], bv[7][2];
#pragma unroll
    for (int kc = 0; kc < 2; ++kc)
      av[kc] = *(const bf16x8*)&Hin[(size_t)(m0 + (lr & 7)) * LDX1 + ko + kc * 32 + lk];
#pragma unroll
    for (int nf = 0; nf < 7; ++nf)
#pragma unroll
      for (int kc = 0; kc < 2; ++kc)
        bv[nf][kc] = *(const bf16x8*)&Wo[(size_t)(nf * 16 + lr) * H_ + ko + kc * 32 + lk];
#pragma unroll
    for (int nf = 0; nf < 7; ++nf)
#pragma unroll
      for (int kc = 0; kc < 2; ++kc)
        acc[nf] = __builtin_amdgcn_mfma_f32_16x16x32_bf16(av[kc], bv[nf][kc], acc[nf], 0, 0, 0);
  }

  // C rows lq*4+r; rows 8..15 duplicate 0..7 -> store lq<2 only
  if (lq < 2) {
#pragma unroll
    for (int nf = 0; nf < 7; ++nf)
#pragma unroll
      for (int r = 0; r < 4; ++r)
        red[wv][lq * 4 + r][nf * 16 + lr] = acc[nf][r];
  }
  __syncthreads();

  for (int idx = tid; idx < 8 * 112; idx += 256) {
    const int ml = idx / 112, n = idx - ml * 112;
    if (n < IN_) {
      const int m = m0 + ml;
      float s = red[0][ml][n] + red[1][ml][n] + red[2][ml][n] + red[3][ml][n] + b_out[n];
      const float pre = s + prev[m * 112 + n];
      prev[m * 112 + n] = pre;
      out[((size_t)m * SEQ + t) * IN_ + n] = pre;
      X0n[(size_t)m * LDX0 + n] = (bf16)pre;
    }
  }
}

// ---------------------------------------------------------------------------
// init: h0 = mean(hidden), h1 = (global_t + sum hidden)/51, c0 = c1 = mean(cell)
// ---------------------------------------------------------------------------
__global__ void init_state(const float* __restrict__ hs, const float* __restrict__ cs,
                           const float* __restrict__ gts,
                           bf16* __restrict__ X0a, bf16* __restrict__ X1a,
                           float* __restrict__ c0, float* __restrict__ c1)
{
  const int h4 = blockIdx.x * 256 + threadIdx.x;
  if (h4 >= 528) return;
  const int b = blockIdx.y;
  const float4* hp = (const float4*)(hs + (size_t)b * TENC * H_) + h4;
  const float4* cp = (const float4*)(cs + (size_t)b * TENC * H_) + h4;
  float4 sh = {0.f, 0.f, 0.f, 0.f}, sc = {0.f, 0.f, 0.f, 0.f};
  for (int tt = 0; tt < TENC; ++tt) {
    float4 a = hp[tt * 528];
    sh.x += a.x; sh.y += a.y; sh.z += a.z; sh.w += a.w;
    float4 c = cp[tt * 528];
    sc.x += c.x; sc.y += c.y; sc.z += c.z; sc.w += c.w;
  }
  const float4 g = ((const float4*)(gts + (size_t)b * H_))[h4];
  const float4 c0v = {sc.x / 50.f, sc.y / 50.f, sc.z / 50.f, sc.w / 50.f};
  ((float4*)(c0 + (size_t)b * H_))[h4] = c0v;
  ((float4*)(c1 + (size_t)b * H_))[h4] = c0v;
  bf16x4 h0b = {(bf16)(sh.x / 50.f), (bf16)(sh.y / 50.f), (bf16)(sh.z / 50.f), (bf16)(sh.w / 50.f)};
  *(bf16x4*)&X0a[(size_t)b * LDX0 + 128 + h4 * 4] = h0b;
  bf16x4 h1b = {(bf16)((sh.x + g.x) / 51.f), (bf16)((sh.y + g.y) / 51.f),
                (bf16)((sh.z + g.z) / 51.f), (bf16)((sh.w + g.w) / 51.f)};
  *(bf16x4*)&X1a[(size_t)b * LDX1 + 2112 + h4 * 4] = h1b;
}

__global__ void init_prev(const float* __restrict__ p, float* __restrict__ prev,
                          bf16* __restrict__ X0a, bf16* __restrict__ X0b)
{
  const int idx = blockIdx.x * 256 + threadIdx.x;   // B*128
  const int b = idx >> 7, n = idx & 127;
  const float v = (n < IN_) ? p[(size_t)b * IN_ + n] : 0.f;
  if (n < 112) prev[b * 112 + n] = v;
  X0a[(size_t)b * LDX0 + n] = (bf16)v;
  X0b[(size_t)b * LDX0 + n] = (bf16)0.f;   // pads (cols 99..128) stay zero; 0..99 overwritten step 0
}

// ---------------------------------------------------------------------------
// weight packing (fp32 -> bf16, concatenated / transposed)
// ---------------------------------------------------------------------------
__global__ void pack_w0(const float* __restrict__ Wih, const float* __restrict__ Whh,
                        bf16* __restrict__ Wc)
{
  const int n = blockIdx.x;
  const float* a = Wih + (size_t)n * IN_;
  const float* b = Whh + (size_t)n * H_;
  bf16* d = Wc + (size_t)n * K0;
  for (int k = threadIdx.x; k < K0; k += 256) {
    float v = (k < IN_) ? a[k] : ((k >= 128) ? b[k - 128] : 0.f);
    d[k] = (bf16)v;
  }
}

__global__ void pack_w1(const float* __restrict__ Wih, const float* __restrict__ Whh,
                        bf16* __restrict__ Wc)
{
  const int n = blockIdx.x;
  bf16* d = Wc + (size_t)n * K1;
  for (int k = threadIdx.x; k < K1; k += 256)
    d[k] = (bf16)((k < H_) ? Wih[(size_t)n * H_ + k] : Whh[(size_t)n * H_ + k - H_]);
}

__global__ void pack_wo(const float* __restrict__ W, bf16* __restrict__ Wo)
{
  const int n = blockIdx.x;   // 0..111
  for (int k = threadIdx.x; k < H_; k += 256)
    Wo[(size_t)n * H_ + k] = (n < IN_) ? (bf16)W[(size_t)k * IN_ + n] : (bf16)0.f;
}

__global__ void pack_bias(const float* __restrict__ bi0, const float* __restrict__ bh0,
                          const float* __restrict__ bi1, const float* __restrict__ bh1,
                          float* __restrict__ bs0, float* __restrict__ bs1)
{
  const int i = blockIdx.x * 256 + threadIdx.x;
  if (i < FH) { bs0[i] = bi0[i] + bh0[i]; bs1[i] = bi1[i] + bh1[i]; }
}

// ---------------------------------------------------------------------------
extern "C" void kernel_launch(void* const* d_in, const int* in_sizes, int n_in,
                              void* d_out, int out_size, void* d_ws, size_t ws_size,
                              hipStream_t stream)
{
  (void)in_sizes; (void)n_in; (void)out_size; (void)ws_size;
  const float* hs   = (const float*)d_in[0];
  const float* cs   = (const float*)d_in[1];
  const float* gts  = (const float*)d_in[2];
  const float* p    = (const float*)d_in[3];
  const float* Wih0 = (const float*)d_in[4];
  const float* bih0 = (const float*)d_in[5];
  const float* Whh0 = (const float*)d_in[6];
  const float* bhh0 = (const float*)d_in[7];
  const float* Wih1 = (const float*)d_in[8];
  const float* bih1 = (const float*)d_in[9];
  const float* Whh1 = (const float*)d_in[10];
  const float* bhh1 = (const float*)d_in[11];
  const float* Wout = (const float*)d_in[12];
  const float* bout = (const float*)d_in[13];
  float* out = (float*)d_out;

  char* ws = (char*)d_ws;
  size_t off = 0;
  auto alloc = [&](size_t bytes) -> void* {
    void* q = ws + off; off += (bytes + 255) & ~(size_t)255; return q;
  };
  bf16* Wc0 = (bf16*)alloc((size_t)FH * K0 * 2);
  bf16* Wc1 = (bf16*)alloc((size_t)FH * K1 * 2);
  bf16* Wo  = (bf16*)alloc((size_t)112 * H_ * 2);
  float* bs0 = (float*)alloc((size_t)FH * 4);
  float* bs1 = (float*)alloc((size_t)FH * 4);
  bf16* X0[2] = {(bf16*)alloc((size_t)B_ * LDX0 * 2), (bf16*)alloc((size_t)B_ * LDX0 * 2)};
  bf16* X1[2] = {(bf16*)alloc((size_t)B_ * LDX1 * 2), (bf16*)alloc((size_t)B_ * LDX1 * 2)};
  float* c0  = (float*)alloc((size_t)B_ * H_ * 4);
  float* c1  = (float*)alloc((size_t)B_ * H_ * 4);
  float* prev = (float*)alloc((size_t)B_ * 112 * 4);

  pack_w0<<<FH, 256, 0, stream>>>(Wih0, Whh0, Wc0);
  pack_w1<<<FH, 256, 0, stream>>>(Wih1, Whh1, Wc1);
  pack_wo<<<112, 256, 0, stream>>>(Wout, Wo);
  pack_bias<<<(FH + 255) / 256, 256, 0, stream>>>(bih0, bhh0, bih1, bhh1, bs0, bs1);
  init_prev<<<(B_ * 128) / 256, 256, 0, stream>>>(p, prev, X0[0], X0[1]);
  init_state<<<dim3(3, B_), 256, 0, stream>>>(hs, cs, gts, X0[0], X1[0], c0, c1);

  for (int t = 0; t < SEQ; ++t) {
    const int cur = t & 1, nxt = cur ^ 1;
    // layer 0: reads X0[cur] = [prev_bf | h0]; writes c0, h0n -> X1[cur] cols 0.. and X0[nxt] cols 128..
    lstm_gemm_cell<<<1056, 128, 0, stream>>>(
        X0[cur], LDX0, K0, Wc0, bs0, c0, X1[cur], LDX1, X0[nxt] + 128, LDX0);
    // layer 1: reads X1[cur] = [h0n | h1]; writes c1, h1n -> X1[nxt] cols 2112..
    lstm_gemm_cell<<<1056, 128, 0, stream>>>(
        X1[cur], LDX1, K1, Wc1, bs1, c1, X1[nxt] + 2112, LDX1, (bf16*)nullptr, 0);
    // out: pre = h1n @ W_out + b_out + prev; writes out[:,t,:], prev, X0[nxt] cols 0..99
    out_gemm<<<128, 256, 0, stream>>>(X1[nxt] + 2112, Wo, bout, prev, X0[nxt], out, t);
  }
}

// Round 4
// 4665.935 us; speedup vs baseline: 1.3453x; 1.0805x over previous
//
#include <hip/hip_runtime.h>

#define B_    1024
#define H_    2112
#define FH    8448   // 4*H
#define IN_   99
#define TENC  50
#define SEQ   25
#define K0    2240   // 128 (padded IN) + 2112
#define K1    4224   // 2112 + 2112
#define LDX0  2240
#define LDX1  4224

typedef __bf16 bf16;
typedef __bf16 bf16x8 __attribute__((ext_vector_type(8)));
typedef __bf16 bf16x4 __attribute__((ext_vector_type(4)));
typedef float  f32x4  __attribute__((ext_vector_type(4)));

__device__ __forceinline__ void gload_lds16(const void* g, void* l) {
  __builtin_amdgcn_global_load_lds(
      (const __attribute__((address_space(1))) void*)g,
      (__attribute__((address_space(3))) void*)l, 16, 0, 0);
}

__device__ __forceinline__ float sigf(float x) { return 1.f / (1.f + __expf(-x)); }
__device__ __forceinline__ float tanhfast(float x) { return 1.f - 2.f / (__expf(2.f * x) + 1.f); }

// ---------------------------------------------------------------------------
// Fused gates-GEMM + LSTM cell.
// Tile: 128(M) x 16(h) => 64 gate-cols (sections i,f,g,o at nf=0..3).
// 2 waves (128 thr), 24KB LDS; 1056 blocks (8M x 132h), XCD-chunked.
// T2 XOR-swizzle (m173 pattern): LDS dest linear, global source column
// pre-swizzled by row&7, ds_read applies the same involution.
// ---------------------------------------------------------------------------
__global__ __launch_bounds__(128, 3)
void lstm_gemm_cell(const bf16* __restrict__ X, int lda, int K,
                    const bf16* __restrict__ W,
                    const float* __restrict__ bsum,   // 4H combined bias
                    float* __restrict__ Cst,          // B x H fp32, in-place
                    bf16* __restrict__ d1, int ld1,   // h_new dest 1
                    bf16* __restrict__ d2, int ld2)   // h_new dest 2 (optional)
{
  __shared__ __align__(16) bf16 As[128 * 64];   // 16 KB
  __shared__ __align__(16) bf16 Bs[64 * 64];    //  8 KB

  // XCD-chunked: 1056 blocks, 132 consecutive vids per XCD; vid is hc-major so
  // the 8 same-weight-panel M-blocks are adjacent -> weight panel L2-resident.
  const int cpx = gridDim.x >> 3;                       // 132
  const int vid = (blockIdx.x & 7) * cpx + (blockIdx.x >> 3);
  const int hc0 = (vid >> 3) * 16;                      // 0..2096
  const int m0  = (vid & 7) * 128;

  const int tid  = threadIdx.x;                         // 0..127
  const int srow = tid >> 3;                            // 0..15
  // T2: physical 16B-unit (tid&7) must hold logical unit (tid&7)^(srow&7);
  // achieved by reading the global source at the swizzled column.
  const int scol = ((tid & 7) ^ (srow & 7)) * 8;        // bf16 elems

  const bf16* Ab = X + (size_t)(m0 + srow) * lda + scol;
  const bf16* Bb = W + (size_t)(hc0 + srow) * K + scol; // + sec*H*K per section

  const int lane = tid & 63;
  const int w    = tid >> 6;                            // wave 0/1
  const int lr   = lane & 15, lq = lane >> 4;
  const int xs   = lr & 7;                              // read-row parity
  // swizzled fragment column offsets (bf16 elems) for kc = 0,1
  const int cof0 = (lq ^ xs) * 8;
  const int cof1 = ((4 + lq) ^ xs) * 8;

  f32x4 acc[4][4];
#pragma unroll
  for (int a = 0; a < 4; ++a)
#pragma unroll
    for (int b = 0; b < 4; ++b) acc[a][b] = (f32x4){0.f, 0.f, 0.f, 0.f};

  const int KT = K >> 6;
  for (int kt = 0; kt < KT; ++kt) {
    const int ko = kt * 64;
    // A: 128 rows x 64 cols, 8 iters x (128 thr x 16B); LDS dest linear.
#pragma unroll
    for (int it = 0; it < 8; ++it)
      gload_lds16(Ab + (size_t)it * 16 * lda + ko, &As[it * 1024 + tid * 8]);
    // B: 64 gate-rows (4 sections x 16 h-rows) x 64 cols
#pragma unroll
    for (int it = 0; it < 4; ++it)
      gload_lds16(Bb + (size_t)it * H_ * K + ko, &Bs[it * 1024 + tid * 8]);
    __syncthreads();

    bf16x8 af[4][2], bfr[4][2];
#pragma unroll
    for (int mi = 0; mi < 4; ++mi) {
      const int r = (w * 64 + mi * 16 + lr) * 64;       // row&7 == lr&7
      af[mi][0] = *(const bf16x8*)&As[r + cof0];
      af[mi][1] = *(const bf16x8*)&As[r + cof1];
    }
#pragma unroll
    for (int nf = 0; nf < 4; ++nf) {
      const int r = (nf * 16 + lr) * 64;                // row&7 == lr&7
      bfr[nf][0] = *(const bf16x8*)&Bs[r + cof0];
      bfr[nf][1] = *(const bf16x8*)&Bs[r + cof1];
    }
#pragma unroll
    for (int mi = 0; mi < 4; ++mi)
#pragma unroll
      for (int nf = 0; nf < 4; ++nf)
#pragma unroll
        for (int kc = 0; kc < 2; ++kc)
          acc[mi][nf] = __builtin_amdgcn_mfma_f32_16x16x32_bf16(
              af[mi][kc], bfr[nf][kc], acc[mi][nf], 0, 0, 0);
    __syncthreads();
  }

  // epilogue: LSTM cell (lane owns h-col hc for 16 m-rows)
  const int hc = hc0 + lr;
  const float bi  = bsum[hc];
  const float bff = bsum[H_ + hc];
  const float bg  = bsum[2 * H_ + hc];
  const float bo  = bsum[3 * H_ + hc];

#pragma unroll
  for (int mi = 0; mi < 4; ++mi) {
#pragma unroll
    for (int r = 0; r < 4; ++r) {
      const int m = m0 + w * 64 + mi * 16 + lq * 4 + r;
      const float gi = acc[mi][0][r] + bi;
      const float gf = acc[mi][1][r] + bff;
      const float gg = acc[mi][2][r] + bg;
      const float go = acc[mi][3][r] + bo;
      const size_t ci = (size_t)m * H_ + hc;
      const float c_old = Cst[ci];
      const float cn = sigf(gf) * c_old + sigf(gi) * tanhfast(gg);
      const float hn = sigf(go) * tanhfast(cn);
      Cst[ci] = cn;
      const bf16 hb = (bf16)hn;
      d1[(size_t)m * ld1 + hc] = hb;
      if (d2) d2[(size_t)m * ld2 + hc] = hb;
    }
  }
}

// ---------------------------------------------------------------------------
// out-GEMM: pre = h1n @ W_out + b_out + prev ; writes d_out, prev, X0next bf16.
// 128 blocks of 8 rows (A-frag rows duplicated lr&7); K=2112 as 33 tiles of 64
// split {9,8,8,8} across 4 waves; LDS reduce.
// ---------------------------------------------------------------------------
__global__ __launch_bounds__(256, 1)
void out_gemm(const bf16* __restrict__ Hin,   // X1next + 2112, row stride 4224
              const bf16* __restrict__ Wo,    // 112 x 2112 (transposed W_out, zero-padded)
              const float* __restrict__ b_out,
              float* __restrict__ prev,       // B x 112 fp32
              bf16* __restrict__ X0n,         // write bf16 pre at cols 0..99
              float* __restrict__ out, int t)
{
  __shared__ float red[4][8][112];
  const int tid = threadIdx.x;
  const int m0 = blockIdx.x * 8;
  const int lane = tid & 63, wv = tid >> 6;
  const int lr = lane & 15, lq = lane >> 4, lk = lq * 8;

  f32x4 acc[7];
#pragma unroll
  for (int b = 0; b < 7; ++b) acc[b] = (f32x4){0.f, 0.f, 0.f, 0.f};

  const int start = (wv == 0) ? 0 : (1 + wv * 8);   // {0,9,17,25}
  const int cnt = (wv == 0) ? 9 : 8;                // 33 K-tiles of 64 total

  for (int kt = start; kt < start + cnt; ++kt) {
    const int ko = kt * 64;
    bf16x8 av[2], bv[7][2];
#pragma unroll
    for (int kc = 0; kc < 2; ++kc)
      av[kc] = *(const bf16x8*)&Hin[(size_t)(m0 + (lr & 7)) * LDX1 + ko + kc * 32 + lk];
#pragma unroll
    for (int nf = 0; nf < 7; ++nf)
#pragma unroll
      for (int kc = 0; kc < 2; ++kc)
        bv[nf][kc] = *(const bf16x8*)&Wo[(size_t)(nf * 16 + lr) * H_ + ko + kc * 32 + lk];
#pragma unroll
    for (int nf = 0; nf < 7; ++nf)
#pragma unroll
      for (int kc = 0; kc < 2; ++kc)
        acc[nf] = __builtin_amdgcn_mfma_f32_16x16x32_bf16(av[kc], bv[nf][kc], acc[nf], 0, 0, 0);
  }

  // C rows lq*4+r; rows 8..15 duplicate 0..7 -> store lq<2 only
  if (lq < 2) {
#pragma unroll
    for (int nf = 0; nf < 7; ++nf)
#pragma unroll
      for (int r = 0; r < 4; ++r)
        red[wv][lq * 4 + r][nf * 16 + lr] = acc[nf][r];
  }
  __syncthreads();

  for (int idx = tid; idx < 8 * 112; idx += 256) {
    const int ml = idx / 112, n = idx - ml * 112;
    if (n < IN_) {
      const int m = m0 + ml;
      float s = red[0][ml][n] + red[1][ml][n] + red[2][ml][n] + red[3][ml][n] + b_out[n];
      const float pre = s + prev[m * 112 + n];
      prev[m * 112 + n] = pre;
      out[((size_t)m * SEQ + t) * IN_ + n] = pre;
      X0n[(size_t)m * LDX0 + n] = (bf16)pre;
    }
  }
}

// ---------------------------------------------------------------------------
// init: h0 = mean(hidden), h1 = (global_t + sum hidden)/51, c0 = c1 = mean(cell)
// ---------------------------------------------------------------------------
__global__ void init_state(const float* __restrict__ hs, const float* __restrict__ cs,
                           const float* __restrict__ gts,
                           bf16* __restrict__ X0a, bf16* __restrict__ X1a,
                           float* __restrict__ c0, float* __restrict__ c1)
{
  const int h4 = blockIdx.x * 256 + threadIdx.x;
  if (h4 >= 528) return;
  const int b = blockIdx.y;
  const float4* hp = (const float4*)(hs + (size_t)b * TENC * H_) + h4;
  const float4* cp = (const float4*)(cs + (size_t)b * TENC * H_) + h4;
  float4 sh = {0.f, 0.f, 0.f, 0.f}, sc = {0.f, 0.f, 0.f, 0.f};
  for (int tt = 0; tt < TENC; ++tt) {
    float4 a = hp[tt * 528];
    sh.x += a.x; sh.y += a.y; sh.z += a.z; sh.w += a.w;
    float4 c = cp[tt * 528];
    sc.x += c.x; sc.y += c.y; sc.z += c.z; sc.w += c.w;
  }
  const float4 g = ((const float4*)(gts + (size_t)b * H_))[h4];
  const float4 c0v = {sc.x / 50.f, sc.y / 50.f, sc.z / 50.f, sc.w / 50.f};
  ((float4*)(c0 + (size_t)b * H_))[h4] = c0v;
  ((float4*)(c1 + (size_t)b * H_))[h4] = c0v;
  bf16x4 h0b = {(bf16)(sh.x / 50.f), (bf16)(sh.y / 50.f), (bf16)(sh.z / 50.f), (bf16)(sh.w / 50.f)};
  *(bf16x4*)&X0a[(size_t)b * LDX0 + 128 + h4 * 4] = h0b;
  bf16x4 h1b = {(bf16)((sh.x + g.x) / 51.f), (bf16)((sh.y + g.y) / 51.f),
                (bf16)((sh.z + g.z) / 51.f), (bf16)((sh.w + g.w) / 51.f)};
  *(bf16x4*)&X1a[(size_t)b * LDX1 + 2112 + h4 * 4] = h1b;
}

__global__ void init_prev(const float* __restrict__ p, float* __restrict__ prev,
                          bf16* __restrict__ X0a, bf16* __restrict__ X0b)
{
  const int idx = blockIdx.x * 256 + threadIdx.x;   // B*128
  const int b = idx >> 7, n = idx & 127;
  const float v = (n < IN_) ? p[(size_t)b * IN_ + n] : 0.f;
  if (n < 112) prev[b * 112 + n] = v;
  X0a[(size_t)b * LDX0 + n] = (bf16)v;
  X0b[(size_t)b * LDX0 + n] = (bf16)0.f;   // pads (cols 99..128) stay zero; 0..99 overwritten step 0
}

// ---------------------------------------------------------------------------
// weight packing (fp32 -> bf16, concatenated / transposed)
// ---------------------------------------------------------------------------
__global__ void pack_w0(const float* __restrict__ Wih, const float* __restrict__ Whh,
                        bf16* __restrict__ Wc)
{
  const int n = blockIdx.x;
  const float* a = Wih + (size_t)n * IN_;
  const float* b = Whh + (size_t)n * H_;
  bf16* d = Wc + (size_t)n * K0;
  for (int k = threadIdx.x; k < K0; k += 256) {
    float v = (k < IN_) ? a[k] : ((k >= 128) ? b[k - 128] : 0.f);
    d[k] = (bf16)v;
  }
}

__global__ void pack_w1(const float* __restrict__ Wih, const float* __restrict__ Whh,
                        bf16* __restrict__ Wc)
{
  const int n = blockIdx.x;
  bf16* d = Wc + (size_t)n * K1;
  for (int k = threadIdx.x; k < K1; k += 256)
    d[k] = (bf16)((k < H_) ? Wih[(size_t)n * H_ + k] : Whh[(size_t)n * H_ + k - H_]);
}

__global__ void pack_wo(const float* __restrict__ W, bf16* __restrict__ Wo)
{
  const int n = blockIdx.x;   // 0..111
  for (int k = threadIdx.x; k < H_; k += 256)
    Wo[(size_t)n * H_ + k] = (n < IN_) ? (bf16)W[(size_t)k * IN_ + n] : (bf16)0.f;
}

__global__ void pack_bias(const float* __restrict__ bi0, const float* __restrict__ bh0,
                          const float* __restrict__ bi1, const float* __restrict__ bh1,
                          float* __restrict__ bs0, float* __restrict__ bs1)
{
  const int i = blockIdx.x * 256 + threadIdx.x;
  if (i < FH) { bs0[i] = bi0[i] + bh0[i]; bs1[i] = bi1[i] + bh1[i]; }
}

// ---------------------------------------------------------------------------
extern "C" void kernel_launch(void* const* d_in, const int* in_sizes, int n_in,
                              void* d_out, int out_size, void* d_ws, size_t ws_size,
                              hipStream_t stream)
{
  (void)in_sizes; (void)n_in; (void)out_size; (void)ws_size;
  const float* hs   = (const float*)d_in[0];
  const float* cs   = (const float*)d_in[1];
  const float* gts  = (const float*)d_in[2];
  const float* p    = (const float*)d_in[3];
  const float* Wih0 = (const float*)d_in[4];
  const float* bih0 = (const float*)d_in[5];
  const float* Whh0 = (const float*)d_in[6];
  const float* bhh0 = (const float*)d_in[7];
  const float* Wih1 = (const float*)d_in[8];
  const float* bih1 = (const float*)d_in[9];
  const float* Whh1 = (const float*)d_in[10];
  const float* bhh1 = (const float*)d_in[11];
  const float* Wout = (const float*)d_in[12];
  const float* bout = (const float*)d_in[13];
  float* out = (float*)d_out;

  char* ws = (char*)d_ws;
  size_t off = 0;
  auto alloc = [&](size_t bytes) -> void* {
    void* q = ws + off; off += (bytes + 255) & ~(size_t)255; return q;
  };
  bf16* Wc0 = (bf16*)alloc((size_t)FH * K0 * 2);
  bf16* Wc1 = (bf16*)alloc((size_t)FH * K1 * 2);
  bf16* Wo  = (bf16*)alloc((size_t)112 * H_ * 2);
  float* bs0 = (float*)alloc((size_t)FH * 4);
  float* bs1 = (float*)alloc((size_t)FH * 4);
  bf16* X0[2] = {(bf16*)alloc((size_t)B_ * LDX0 * 2), (bf16*)alloc((size_t)B_ * LDX0 * 2)};
  bf16* X1[2] = {(bf16*)alloc((size_t)B_ * LDX1 * 2), (bf16*)alloc((size_t)B_ * LDX1 * 2)};
  float* c0  = (float*)alloc((size_t)B_ * H_ * 4);
  float* c1  = (float*)alloc((size_t)B_ * H_ * 4);
  float* prev = (float*)alloc((size_t)B_ * 112 * 4);

  pack_w0<<<FH, 256, 0, stream>>>(Wih0, Whh0, Wc0);
  pack_w1<<<FH, 256, 0, stream>>>(Wih1, Whh1, Wc1);
  pack_wo<<<112, 256, 0, stream>>>(Wout, Wo);
  pack_bias<<<(FH + 255) / 256, 256, 0, stream>>>(bih0, bhh0, bih1, bhh1, bs0, bs1);
  init_prev<<<(B_ * 128) / 256, 256, 0, stream>>>(p, prev, X0[0], X0[1]);
  init_state<<<dim3(3, B_), 256, 0, stream>>>(hs, cs, gts, X0[0], X1[0], c0, c1);

  for (int t = 0; t < SEQ; ++t) {
    const int cur = t & 1, nxt = cur ^ 1;
    // layer 0: reads X0[cur] = [prev_bf | h0]; writes c0, h0n -> X1[cur] cols 0.. and X0[nxt] cols 128..
    lstm_gemm_cell<<<1056, 128, 0, stream>>>(
        X0[cur], LDX0, K0, Wc0, bs0, c0, X1[cur], LDX1, X0[nxt] + 128, LDX0);
    // layer 1: reads X1[cur] = [h0n | h1]; writes c1, h1n -> X1[nxt] cols 2112..
    lstm_gemm_cell<<<1056, 128, 0, stream>>>(
        X1[cur], LDX1, K1, Wc1, bs1, c1, X1[nxt] + 2112, LDX1, (bf16*)nullptr, 0);
    // out: pre = h1n @ W_out + b_out + prev; writes out[:,t,:], prev, X0[nxt] cols 0..99
    out_gemm<<<128, 256, 0, stream>>>(X1[nxt] + 2112, Wo, bout, prev, X0[nxt], out, t);
  }
}